// Round 8
// baseline (177.057 us; speedup 1.0000x reference)
//
#include <hip/hip_runtime.h>

#define N_NODES 100000
#define N_EDGES 1600000
#define LAT 128
#define MAT 8
#define OUTC 3

#define NBKT 391          // ceil(N_NODES / 256) buckets of 256 nodes
#define CAP  4608         // per-bucket region capacity (mean 4096, sigma 64)
#define CHUNK 4096        // edges per binA block

typedef __attribute__((ext_vector_type(8))) short bf16x8;
typedef __attribute__((ext_vector_type(4))) float f32x4;

__device__ __forceinline__ unsigned short bf16r(float f) {   // RTNE fp32->bf16
    unsigned int u = __float_as_uint(f);
    u = (u + 0x7fffu + ((u >> 16) & 1u)) >> 16;
    return (unsigned short)u;
}
__device__ __forceinline__ float bf16f(unsigned short h) {
    return __uint_as_float((unsigned int)h << 16);
}

// ---------------- Pass A: coarse bin by dst>>8, LDS-staged for coalesced writes ----------------
__global__ __launch_bounds__(256) void k_binA(const int* __restrict__ src,
                                              const int* __restrict__ dst,
                                              int* __restrict__ gcount,
                                              unsigned int* __restrict__ binned) {
    __shared__ int hist[NBKT];
    __shared__ int adj[NBKT];            // gbase - local_exclusive_prefix
    __shared__ int cur[NBKT];            // local scatter cursor
    __shared__ int wsum[4];
    __shared__ unsigned int lbuf[CHUNK];
    __shared__ unsigned short lbkt[CHUNK];

    int t = threadIdx.x;
    int base = blockIdx.x * CHUNK;
    int nEdge = min(CHUNK, N_EDGES - base);

    for (int i = t; i < NBKT; i += 256) hist[i] = 0;
    __syncthreads();

    unsigned int pk[16];
    unsigned short bk[16];
#pragma unroll
    for (int j = 0; j < 16; ++j) {
        int li = j * 256 + t;
        if (li < nEdge) {
            int e = base + li;
            int d = dst[e];
            int s = src[e];
            pk[j] = ((unsigned int)s << 8) | (unsigned int)(d & 255);
            bk[j] = (unsigned short)(d >> 8);
            atomicAdd(&hist[bk[j]], 1);
        } else {
            bk[j] = 0xffffu;
        }
    }
    __syncthreads();

    // exclusive scan over 391 buckets: each thread owns pair (2t, 2t+1)
    int lane = t & 63, w = t >> 6;
    int i0 = 2 * t, i1 = 2 * t + 1;
    int h0 = (i0 < NBKT) ? hist[i0] : 0;
    int h1 = (i1 < NBKT) ? hist[i1] : 0;
    int ps = h0 + h1;
    int x = ps;
#pragma unroll
    for (int off = 1; off < 64; off <<= 1) {
        int y = __shfl_up(x, off, 64);
        if (lane >= off) x += y;
    }
    if (lane == 63) wsum[w] = x;
    __syncthreads();
    int woff = 0;
#pragma unroll
    for (int i = 0; i < 4; ++i)
        if (i < w) woff += wsum[i];
    int excl = woff + x - ps;   // exclusive prefix of element i0
    if (i0 < NBKT) {
        int g0 = i0 * CAP + atomicAdd(&gcount[i0], h0);
        adj[i0] = g0 - excl;
        cur[i0] = excl;
    }
    if (i1 < NBKT) {
        int g1r = i1 * CAP + atomicAdd(&gcount[i1], h1);
        adj[i1] = g1r - (excl + h0);
        cur[i1] = excl + h0;
    }
    __syncthreads();

    // local scatter into bucket-sorted LDS order
#pragma unroll
    for (int j = 0; j < 16; ++j) {
        if (bk[j] != 0xffffu) {
            int pos = atomicAdd(&cur[bk[j]], 1);
            lbuf[pos] = pk[j];
            lbkt[pos] = bk[j];
        }
    }
    __syncthreads();

    // linear, coalesced write-out: contiguous within-bucket chunks
    for (int i = t; i < nEdge; i += 256) {
        int b = lbkt[i];
        binned[adj[b] + i] = lbuf[i];
    }
}

// ---------------- scan of 391 bucket counts -> bucketBase ----------------
__global__ __launch_bounds__(256) void k_bscan(const int* __restrict__ gcount,
                                               int* __restrict__ bucketBase,
                                               int* __restrict__ rowptr) {
    __shared__ int wsum[4];
    int t = threadIdx.x;
    int lane = t & 63, w = t >> 6;
    int i0 = 2 * t, i1 = 2 * t + 1;
    int h0 = (i0 < NBKT) ? gcount[i0] : 0;
    int h1 = (i1 < NBKT) ? gcount[i1] : 0;
    int ps = h0 + h1;
    int x = ps;
#pragma unroll
    for (int off = 1; off < 64; off <<= 1) {
        int y = __shfl_up(x, off, 64);
        if (lane >= off) x += y;
    }
    if (lane == 63) wsum[w] = x;
    __syncthreads();
    int woff = 0;
#pragma unroll
    for (int i = 0; i < 4; ++i)
        if (i < w) woff += wsum[i];
    int excl = woff + x - ps;
    bucketBase[i0] = excl;
    bucketBase[i1] = excl + h0;
    if (t == 0) rowptr[N_NODES] = N_EDGES;
}

// ---------------- Pass B: fine sort within bucket, emit colsrc + rowptr + dinv ----------------
__global__ __launch_bounds__(256) void k_binB(const unsigned int* __restrict__ binned,
                                              const int* __restrict__ gcount,
                                              const int* __restrict__ bucketBase,
                                              int* __restrict__ colsrc,
                                              int* __restrict__ rowptr,
                                              float* __restrict__ dinv) {
    __shared__ unsigned int lbuf[CAP];
    __shared__ int lsrc[CAP];
    __shared__ int hist[256];
    __shared__ int cur[256];
    __shared__ int wsum[4];

    int b = blockIdx.x, t = threadIdx.x;
    int cnt = min(gcount[b], CAP);
    int gb = bucketBase[b];
    const unsigned int* bp = binned + (size_t)b * CAP;

    for (int i = t; i < cnt; i += 256) lbuf[i] = bp[i];
    hist[t] = 0;
    __syncthreads();
    for (int i = t; i < cnt; i += 256) atomicAdd(&hist[lbuf[i] & 255], 1);
    __syncthreads();

    // exclusive scan of hist[256]
    int lane = t & 63, w = t >> 6;
    int h = hist[t];
    int x = h;
#pragma unroll
    for (int off = 1; off < 64; off <<= 1) {
        int y = __shfl_up(x, off, 64);
        if (lane >= off) x += y;
    }
    if (lane == 63) wsum[w] = x;
    __syncthreads();
    int woff = 0;
#pragma unroll
    for (int i = 0; i < 4; ++i)
        if (i < w) woff += wsum[i];
    int excl = woff + x - h;
    cur[t] = excl;

    int node = b * 256 + t;
    if (node < N_NODES) {
        rowptr[node] = gb + excl;
        dinv[node] = rsqrtf((float)h + 1.0f);   // +1 self-loop
    }
    __syncthreads();

    for (int i = t; i < cnt; i += 256) {
        unsigned int p = lbuf[i];
        int pos = atomicAdd(&cur[p & 255], 1);
        lsrc[pos] = (int)(p >> 8);
    }
    __syncthreads();

    for (int i = t; i < cnt; i += 256) colsrc[gb + i] = lsrc[i];
}

// ---------------- W1 split: fp32 [136][128] -> bf16 hi/lo [160][128], zero-padded ----------------
__global__ void k_wsplit(const float* __restrict__ W1,
                         unsigned short* __restrict__ w1h,
                         unsigned short* __restrict__ w1l) {
    int i = blockIdx.x * 256 + threadIdx.x;
    if (i >= 160 * 128) return;
    int k = i >> 7;
    float w = (k < LAT + MAT) ? W1[i] : 0.f;
    unsigned short h = bf16r(w);
    w1h[i] = h;
    w1l[i] = bf16r(w - bf16f(h));
}

// ---------------- GEMM1 via split-bf16 MFMA ----------------
// g1 = (concat(z,mat) @ W1) * dinv,  x ~= xh + xl (bf16 each), W ~= Wh + Wl.
// x@W ~= xh@Wh + xl@Wh + xh@Wl  (xl@Wl ~ 2^-16 rel, dropped).
__global__ __launch_bounds__(256) void k_gemm1m(const float* __restrict__ z,
                                                const float* __restrict__ mat,
                                                const unsigned short* __restrict__ w1h,
                                                const unsigned short* __restrict__ w1l,
                                                const float* __restrict__ dinv,
                                                unsigned short* __restrict__ g1h) {
    int wv = threadIdx.x >> 6;
    int l = threadIdx.x & 63;
    int lm = l & 15, q = l >> 4;

    // B fragments: B[k][col], lane -> col = base+lm, k = ks*32 + q*8 + j
    bf16x8 bh[2][5], bl[2][5];
#pragma unroll
    for (int ct = 0; ct < 2; ++ct) {
        int col = (wv * 2 + ct) * 16 + lm;
#pragma unroll
        for (int ks = 0; ks < 5; ++ks) {
#pragma unroll
            for (int j = 0; j < 8; ++j) {
                int k = ks * 32 + q * 8 + j;
                bh[ct][ks][j] = (short)w1h[k * 128 + col];
                bl[ct][ks][j] = (short)w1l[k * 128 + col];
            }
        }
    }

    for (int tile = blockIdx.x; tile < N_NODES / 16; tile += gridDim.x) {
        int n0 = tile * 16;
        int row = n0 + lm;                     // A row for this lane
        f32x4 acc0 = {0.f, 0.f, 0.f, 0.f};
        f32x4 acc1 = {0.f, 0.f, 0.f, 0.f};
#pragma unroll
        for (int ks = 0; ks < 5; ++ks) {
            float a[8];
            if (ks < 4) {
                float4 a0 = *(const float4*)&z[(size_t)row * LAT + ks * 32 + q * 8];
                float4 a1 = *(const float4*)&z[(size_t)row * LAT + ks * 32 + q * 8 + 4];
                a[0] = a0.x; a[1] = a0.y; a[2] = a0.z; a[3] = a0.w;
                a[4] = a1.x; a[5] = a1.y; a[6] = a1.z; a[7] = a1.w;
            } else if (q == 0) {               // k = 128..135 -> mat[0..7]
                float4 m0 = *(const float4*)&mat[(size_t)row * MAT];
                float4 m1 = *(const float4*)&mat[(size_t)row * MAT + 4];
                a[0] = m0.x; a[1] = m0.y; a[2] = m0.z; a[3] = m0.w;
                a[4] = m1.x; a[5] = m1.y; a[6] = m1.z; a[7] = m1.w;
            } else {                           // k = 136..159 -> zero pad
#pragma unroll
                for (int j = 0; j < 8; ++j) a[j] = 0.f;
            }
            bf16x8 ah, al;
#pragma unroll
            for (int j = 0; j < 8; ++j) {
                unsigned short h = bf16r(a[j]);
                ah[j] = (short)h;
                al[j] = (short)bf16r(a[j] - bf16f(h));
            }
            acc0 = __builtin_amdgcn_mfma_f32_16x16x32_bf16(ah, bh[0][ks], acc0, 0, 0, 0);
            acc1 = __builtin_amdgcn_mfma_f32_16x16x32_bf16(ah, bh[1][ks], acc1, 0, 0, 0);
            acc0 = __builtin_amdgcn_mfma_f32_16x16x32_bf16(al, bh[0][ks], acc0, 0, 0, 0);
            acc1 = __builtin_amdgcn_mfma_f32_16x16x32_bf16(al, bh[1][ks], acc1, 0, 0, 0);
            acc0 = __builtin_amdgcn_mfma_f32_16x16x32_bf16(ah, bl[0][ks], acc0, 0, 0, 0);
            acc1 = __builtin_amdgcn_mfma_f32_16x16x32_bf16(ah, bl[1][ks], acc1, 0, 0, 0);
        }
        // D layout: col = lm, row = q*4 + r
#pragma unroll
        for (int r = 0; r < 4; ++r) {
            int m = q * 4 + r;
            float d = dinv[n0 + m];
            g1h[(size_t)(n0 + m) * 128 + (wv * 2 + 0) * 16 + lm] = bf16r(acc0[r] * d);
            g1h[(size_t)(n0 + m) * 128 + (wv * 2 + 1) * 16 + lm] = bf16r(acc1[r] * d);
        }
    }
}

// ---------------- gather layer1 + fused 128x3 GEMM2 ----------------
// one wave per node. lane = (group g = l>>4, column quad c = l&15).
// Row (128 bf16 = 16 uint4) read by 16 lanes; 4 edge groups; 8 edges/iter.
// x1 = relu(dinv[n]*(g1[n] + sum g1[src]) + b1); g2[n] = (x1 @ W2) * dinv[n]
__global__ __launch_bounds__(256) void k_gather1(const uint4* __restrict__ g1h4,
                                                 const int* __restrict__ colsrc,
                                                 const int* __restrict__ rowptr,
                                                 const float* __restrict__ dinv,
                                                 const float* __restrict__ b1,
                                                 const float* __restrict__ W2,
                                                 float* __restrict__ g2) {
    int n = blockIdx.x * 4 + (threadIdx.x >> 6);
    int l = threadIdx.x & 63;
    int c = l & 15;      // uint4 index within the 256 B row
    int g = l >> 4;      // edge group

    float ax[8];
#pragma unroll
    for (int j = 0; j < 8; ++j) ax[j] = 0.f;

#define ACC(U) { \
    ax[0] += __uint_as_float((U).x << 16); ax[1] += __uint_as_float((U).x & 0xffff0000u); \
    ax[2] += __uint_as_float((U).y << 16); ax[3] += __uint_as_float((U).y & 0xffff0000u); \
    ax[4] += __uint_as_float((U).z << 16); ax[5] += __uint_as_float((U).z & 0xffff0000u); \
    ax[6] += __uint_as_float((U).w << 16); ax[7] += __uint_as_float((U).w & 0xffff0000u); }

    // self row: only group 0 contributes (others would quadruple-count)
    uint4 a0 = g1h4[(unsigned)n * 16u + c];
    if (g != 0) a0 = make_uint4(0u, 0u, 0u, 0u);
    ACC(a0);

    int e0 = rowptr[n], eEnd = rowptr[n + 1];
    for (int e = e0; e < eEnd; e += 8) {
        int i1 = e + g;
        int i2 = e + 4 + g;
        bool v1 = i1 < eEnd;
        bool v2 = i2 < eEnd;
        int s1 = v1 ? colsrc[i1] : n;     // fallback: self row (resident), zeroed below
        int s2 = v2 ? colsrc[i2] : n;
        uint4 u1 = g1h4[(unsigned)s1 * 16u + c];
        uint4 u2 = g1h4[(unsigned)s2 * 16u + c];
        if (!v1) u1 = make_uint4(0u, 0u, 0u, 0u);
        if (!v2) u2 = make_uint4(0u, 0u, 0u, 0u);
        ACC(u1);
        ACC(u2);
    }
#undef ACC

    // merge the 4 edge groups: lanes {c, c+16, c+32, c+48}
#pragma unroll
    for (int j = 0; j < 8; ++j) {
        ax[j] += __shfl_xor(ax[j], 16, 64);
        ax[j] += __shfl_xor(ax[j], 32, 64);
    }

    float d = dinv[n];
    float4 b1a = ((const float4*)b1)[c * 2];
    float4 b1b = ((const float4*)b1)[c * 2 + 1];
    float xx[8];
    xx[0] = fmaxf(ax[0] * d + b1a.x, 0.f);
    xx[1] = fmaxf(ax[1] * d + b1a.y, 0.f);
    xx[2] = fmaxf(ax[2] * d + b1a.z, 0.f);
    xx[3] = fmaxf(ax[3] * d + b1a.w, 0.f);
    xx[4] = fmaxf(ax[4] * d + b1b.x, 0.f);
    xx[5] = fmaxf(ax[5] * d + b1b.y, 0.f);
    xx[6] = fmaxf(ax[6] * d + b1b.z, 0.f);
    xx[7] = fmaxf(ax[7] * d + b1b.w, 0.f);

    // W2 rows 8c..8c+7 -> 24 consecutive floats at W2[24c], 16 B aligned
    const float4* w2p = (const float4*)(W2 + 24 * c);
    float4 wa = w2p[0], wb = w2p[1], wc = w2p[2], wd = w2p[3], we = w2p[4], wf = w2p[5];
    float p0 = xx[0] * wa.x + xx[1] * wa.w + xx[2] * wb.z + xx[3] * wc.y
             + xx[4] * wd.x + xx[5] * wd.w + xx[6] * we.z + xx[7] * wf.y;
    float p1 = xx[0] * wa.y + xx[1] * wb.x + xx[2] * wb.w + xx[3] * wc.z
             + xx[4] * wd.y + xx[5] * we.x + xx[6] * we.w + xx[7] * wf.z;
    float p2 = xx[0] * wa.z + xx[1] * wb.y + xx[2] * wc.x + xx[3] * wc.w
             + xx[4] * wd.z + xx[5] * we.y + xx[6] * wf.x + xx[7] * wf.w;

    // reduce across the 16 column-quads
#pragma unroll
    for (int off = 1; off < 16; off <<= 1) {
        p0 += __shfl_xor(p0, off, 64);
        p1 += __shfl_xor(p1, off, 64);
        p2 += __shfl_xor(p2, off, 64);
    }
    if (l == 0) ((float4*)g2)[n] = make_float4(p0 * d, p1 * d, p2 * d, 0.f);
}

// ---------------- gather layer2: out = dinv[n]*(g2[n] + sum g2[src]) + b2 ----------------
__global__ void k_gather2(const float* __restrict__ g2, const int* __restrict__ colsrc,
                          const int* __restrict__ rowptr, const float* __restrict__ dinv,
                          const float* __restrict__ b2, float* __restrict__ out) {
    int n = blockIdx.x * blockDim.x + threadIdx.x;
    if (n >= N_NODES) return;
    const float4* gv = (const float4*)g2;
    float4 a = gv[n];
    float s0 = a.x, s1 = a.y, s2 = a.z;
    int eEnd = rowptr[n + 1];
    for (int e = rowptr[n]; e < eEnd; ++e) {
        float4 v = gv[colsrc[e]];
        s0 += v.x; s1 += v.y; s2 += v.z;
    }
    float d = dinv[n];
    out[(size_t)n * 3 + 0] = s0 * d + b2[0];
    out[(size_t)n * 3 + 1] = s1 * d + b2[1];
    out[(size_t)n * 3 + 2] = s2 * d + b2[2];
}

// ---------------- launch ----------------

extern "C" void kernel_launch(void* const* d_in, const int* in_sizes, int n_in,
                              void* d_out, int out_size, void* d_ws, size_t ws_size,
                              hipStream_t stream) {
    const float* z   = (const float*)d_in[0];
    const int*   ei  = (const int*)d_in[1];   // [2, E] int32
    const float* mat = (const float*)d_in[2];
    const float* W1  = (const float*)d_in[3];
    const float* b1  = (const float*)d_in[4];
    const float* W2  = (const float*)d_in[5];
    const float* b2  = (const float*)d_in[6];
    float* out = (float*)d_out;

    const int* srcA = ei;             // row 0 = message source
    const int* dstA = ei + N_EDGES;   // row 1 = message target

    char* ws = (char*)d_ws;
    auto alloc = [&](size_t bytes) {
        char* p = ws;
        ws += (bytes + 255) & ~(size_t)255;
        return p;
    };
    int*   gcount     = (int*)alloc(512 * 4);
    int*   bucketBase = (int*)alloc(512 * 4);
    int*   rowptr     = (int*)alloc((size_t)(N_NODES + 1) * 4);
    float* dinv       = (float*)alloc((size_t)N_NODES * 4);
    int*   colsrc     = (int*)alloc((size_t)N_EDGES * 4);
    unsigned int* g1h = (unsigned int*)alloc((size_t)N_NODES * 64 * 4);  // bf16x2 packed
    float* g2         = (float*)alloc((size_t)N_NODES * 4 * 4);
    unsigned short* w1h = (unsigned short*)alloc(160 * 128 * 2);
    unsigned short* w1l = (unsigned short*)alloc(160 * 128 * 2);
    // binned (7.2 MB) aliases g1h (25.6 MB): lifetimes are disjoint
    unsigned int* binned = g1h;

    hipMemsetAsync(gcount, 0, 512 * 4, stream);
    int nBlocksA = (N_EDGES + CHUNK - 1) / CHUNK;  // 391
    k_binA<<<nBlocksA, 256, 0, stream>>>(srcA, dstA, gcount, binned);
    k_bscan<<<1, 256, 0, stream>>>(gcount, bucketBase, rowptr);
    k_binB<<<NBKT, 256, 0, stream>>>(binned, gcount, bucketBase, colsrc, rowptr, dinv);
    k_wsplit<<<(160 * 128 + 255) / 256, 256, 0, stream>>>(W1, w1h, w1l);
    k_gemm1m<<<1250, 256, 0, stream>>>(z, mat, w1h, w1l, dinv, (unsigned short*)g1h);
    k_gather1<<<N_NODES / 4, 256, 0, stream>>>((const uint4*)g1h, colsrc, rowptr, dinv, b1, W2, g2);
    k_gather2<<<(N_NODES + 255) / 256, 256, 0, stream>>>(g2, colsrc, rowptr, dinv, b2, out);
}